// Round 9
// baseline (972.567 us; speedup 1.0000x reference)
//
#include <hip/hip_runtime.h>
#include <math.h>

#define HH 4096
#define WW 4096
#define NB 64
#define U 8
#define NGR (WW / U)       // 512 groups
#define NBATCH (WW / 32)   // 128 halo batches: 4 groups = 32 cols = 64 entries
#define GATE 80            // lead: batch lookahead needs >= 63 cols + margin

// halo: halo[(blk*WW + e)*2 + s]; s=0 -> producer row 62 (consumer r-2),
// s=1 -> row 63 (r-1). Entry e = value after column e-1 (entry 0 = initial x).
// low32 = float bits, high32 = tag (e+1). Poison never matches tags.
//
// HALO PREFETCH IS BATCHED x4 (round-8 lesson): per-group cadence was
// ~1960 cy = ~230 cy issue + ~1700 cy wait, invariant under gating/RMW/
// store-coalescing/clock changes (heater test killed the throttle theory).
// Hypothesis: compiler handles ATOMIC loads conservatively (no software
// pipelining; waitcnt drains the VMEM queue near each halo_ld) -> one full
// drain per group. Fix: ONE 64-lane atomic load per 4 groups (batch m:
// hsrc[64m + lane], coalesced), tag-check once per batch, per-group unpack
// via register shuffles only. Drain events: 512 -> 128.

__device__ __forceinline__ unsigned long long halo_ld(unsigned long long* p) {
    return __hip_atomic_load(p, __ATOMIC_RELAXED, __HIP_MEMORY_SCOPE_AGENT);
}
__device__ __forceinline__ void halo_st(unsigned long long* p, unsigned long long v) {
    __hip_atomic_store(p, v, __ATOMIC_RELAXED, __HIP_MEMORY_SCOPE_AGENT);
}

__device__ __forceinline__ float f4c(const float4& v, int k) {
    return (k == 0) ? v.x : ((k == 1) ? v.y : ((k == 2) ? v.z : v.w));
}

// shift all 64 lanes down by 1 at VALU speed; lane 0 receives fill's lane-0 value.
__device__ __forceinline__ float wave_shr1(float src, float fill) {
    return __int_as_float(__builtin_amdgcn_update_dpp(
        __float_as_int(fill), __float_as_int(src), 0x138, 0xF, 0xF, false));
}

// HW sin: v_sin_f32 computes sin(2*pi*x). |z| <= 3 here -> |rev| < 0.48,
// no range reduction needed. ~1-2 ulp; recurrence is contractive so the
// error does not accumulate (absmax was 0.0 even with a 2-ulp polynomial).
__device__ __forceinline__ float fast_sin(float z) {
    return __builtin_amdgcn_sinf(z * 0.15915494309189535f);  // 1/(2*pi)
}

#define COLSTEP(M, K)                                                        \
    do {                                                                     \
        float am1 = wave_shr1(a, Hhi[M][K]);                                 \
        float am2 = wave_shr1(am1, Hlo[M][K]);                               \
        const float z = fmaf(am2, f4c(W2v[M][(K) >> 2], (K) & 3),            \
                        fmaf(am1, f4c(W1v[M][(K) >> 2], (K) & 3),            \
                        fmaf(a,   f4c(Wv[M][(K) >> 2],  (K) & 3),            \
                                  f4c(Bv[M][(K) >> 2],  (K) & 3))));         \
        a = fast_sin(z);                                                     \
        Pv[K] = a;  /* register copy, off the a->a chain */                  \
    } while (0)

// batched publish of group starting at column JB: entries JB+1..JB+8.
// Lane l<16 stores entry JB+1+(l>>1), slot l&1, from lane 62+(l&1)'s
// Pv[l>>1]. Contiguous 16-lane x 8B store: 2 write transactions
// (WRITE_SIZE 8208->5136 KB confirmed in round 6).
#define PUBG(JB)                                                             \
    do {                                                                     \
        float pv = 0.0f;                                                     \
        _Pragma("unroll")                                                    \
        for (int k = 0; k < U; ++k) {                                        \
            float t = __shfl(Pv[k], 62 + (lane & 1));                        \
            if ((lane >> 1) == k) pv = t;                                    \
        }                                                                    \
        const int e = (JB) + 1 + (lane >> 1);                                \
        if (lane < 16 && e < WW) {                                           \
            unsigned long long v =                                           \
                ((unsigned long long)(unsigned)(e + 1) << 32) |              \
                (unsigned long long)__float_as_uint(pv);                     \
            halo_st(&hme[(size_t)e * 2 + (lane & 1)], v);                    \
        }                                                                    \
    } while (0)

#define LOADW(M, J)                                                          \
    do {                                                                     \
        const int _j = (J);                                                  \
        Wv[M][0]  = *(const float4*)(wp  + _j);                              \
        Wv[M][1]  = *(const float4*)(wp  + _j + 4);                          \
        W1v[M][0] = *(const float4*)(wp1 + _j);                              \
        W1v[M][1] = *(const float4*)(wp1 + _j + 4);                          \
        W2v[M][0] = *(const float4*)(wp2 + _j);                              \
        W2v[M][1] = *(const float4*)(wp2 + _j + 4);                          \
        Bv[M][0]  = *(const float4*)(bp  + _j);                              \
        Bv[M][1]  = *(const float4*)(bp  + _j + 4);                          \
    } while (0)

// batch m: lane l holds halo[64m + l] = entry 32m + (l>>1), slot l&1.
#define LOADBATCH(DST, M)                                                    \
    do {                                                                     \
        if (blk > 0) DST = halo_ld(&hsrc[(size_t)(M) * 64 + lane]);          \
    } while (0)

// tag-check batch M in REG; probe-first retry (refetch immediately, short
// sleep only between FAILED retries -- cheap stalls self-correct, round 2/3).
#define CHECKBATCH(REG, M)                                                   \
    do {                                                                     \
        if (blk > 0) {                                                       \
            bool ok = ((unsigned)((REG) >> 32) ==                            \
                       (unsigned)(32 * (M) + (lane >> 1) + 1));              \
            if (__builtin_expect(!__all(ok), 0)) {                           \
                for (;;) {                                                   \
                    REG = halo_ld(&hsrc[(size_t)(M) * 64 + lane]);           \
                    ok = ((unsigned)((REG) >> 32) ==                         \
                          (unsigned)(32 * (M) + (lane >> 1) + 1));           \
                    if (__all(ok)) break;                                    \
                    __builtin_amdgcn_s_sleep(2);                             \
                }                                                            \
            }                                                                \
        }                                                                    \
    } while (0)

// unpack group index I (0..3) of batch REG into Hlo/Hhi[BUF]: entry
// 32m+8I+k slot0 lives in lane 16I+2k, slot1 in lane 16I+2k+1.
#define UNPACKB(REG, I, BUF)                                                 \
    do {                                                                     \
        if (blk > 0) {                                                       \
            float _hv = __uint_as_float((unsigned)((REG) & 0xffffffffu));    \
            _Pragma("unroll")                                                \
            for (int k = 0; k < U; ++k) {                                    \
                Hlo[BUF][k] = __shfl(_hv, 16 * (I) + 2 * k);                 \
                Hhi[BUF][k] = __shfl(_hv, 16 * (I) + 2 * k + 1);             \
            }                                                                \
        }                                                                    \
    } while (0)

#define GB(S)                                                                \
    do {                                                                     \
        const int jb = (4 * m + (S)) * U;                                    \
        if ((S) < 3) UNPACKB(Hga, (S) + 1, ((S) + 1) & 1);                   \
        _Pragma("unroll")                                                    \
        for (int k = 0; k < U; ++k) COLSTEP((S) & 1, k);                     \
        PUBG(jb);                                                            \
        const int jw = jb + 2 * U;                                           \
        if (jw < WW) LOADW((S) & 1, jw);                                     \
    } while (0)

__global__ __launch_bounds__(64, 1) void neural_grid_scan(
    const float* __restrict__ x, const float* __restrict__ w,
    const float* __restrict__ bb, float* __restrict__ out,
    unsigned long long* __restrict__ halo)
{
    const int lane = threadIdx.x;
    const int blk  = blockIdx.x;
    const int row  = blk * 64 + lane;
    const int r1 = (row >= 1) ? row - 1 : 0;   // am1==0 there, value unused
    const int r2 = (row >= 2) ? row - 2 : 0;

    const float* wp  = w  + (size_t)row * WW;
    const float* wp1 = w  + (size_t)r1  * WW;
    const float* wp2 = w  + (size_t)r2  * WW;
    const float* bp  = bb + (size_t)row * WW;

    unsigned long long* hme  = halo + (size_t)blk * WW * 2;
    unsigned long long* hsrc = halo + (size_t)(blk - 1) * WW * 2;

    float a = x[row];

    // publish initial state (column -1 == x) into entry 0, tag 1 (before gating)
    if (lane >= 62) {
        unsigned long long v = (1ULL << 32) | (unsigned long long)__float_as_uint(a);
        halo_st(&hme[lane - 62], v);
    }

    // ---- start gate: producer GATE columns ahead. Batch lookahead needs
    // lead >= 63 cols (batch m+1's last entry) + margin -> 80.
    if (blk > 0 && lane == 0) {
        while ((unsigned)(halo_ld(&hsrc[(size_t)GATE * 2]) >> 32)
               != (unsigned)(GATE + 1)) {
            __builtin_amdgcn_s_sleep(8);
        }
    }

    float4 Wv[2][2], W1v[2][2], W2v[2][2], Bv[2][2];
    float Hlo[2][U] = {}, Hhi[2][U] = {};
    float Pv[U];
    unsigned long long Hga = 0, Hgb = 0;

    LOADW(0, 0);
    LOADW(1, U);
    LOADBATCH(Hga, 0);
    CHECKBATCH(Hga, 0);
    LOADBATCH(Hgb, 1);
    UNPACKB(Hga, 0, 0);   // group 0 -> buf 0

    for (int m = 0; m < NBATCH; ++m) {
        GB(0);
        GB(1);
        GB(2);
        GB(3);
        if (m + 1 < NBATCH) {
            CHECKBATCH(Hgb, m + 1);       // the ONE vmcnt wait per 4 groups
            Hga = Hgb;
            if (m + 2 < NBATCH) LOADBATCH(Hgb, m + 2);
            UNPACKB(Hga, 0, 0);           // group 4(m+1) -> buf 0
        }
    }

    out[row] = a;
}

extern "C" void kernel_launch(void* const* d_in, const int* in_sizes, int n_in,
                              void* d_out, int out_size, void* d_ws, size_t ws_size,
                              hipStream_t stream) {
    const float* x = (const float*)d_in[0];
    const float* w = (const float*)d_in[1];
    const float* b = (const float*)d_in[2];
    float* out = (float*)d_out;
    unsigned long long* halo = (unsigned long long*)d_ws;
    neural_grid_scan<<<dim3(NB), dim3(64), 0, stream>>>(x, w, b, out, halo);
}